// Round 1
// baseline (700.159 us; speedup 1.0000x reference)
//
#include <hip/hip_runtime.h>

// ---------------------------------------------------------------------------
// LiteMLA: B=4, N=4096, C=1024, D=32, h=32 heads.
//   qkv = x @ W_qkv^T            (16384 x 3072, K=1024)   [relu on q,k cols]
//   per (b,h): vk[d,e] = sum_n Vpad[d,n]*reluK[e,n]   (33x32, reduce N=4096)
//              y[d,n]  = (sum_e vk[d,e]*reluQ[e,n]) / (sum_e vk[32,e]*reluQ[e,n] + eps)
//   out = y @ W_proj^T + b_proj  (16384 x 1024, K=1024)
// All GEMMs: NT (A row-major MxK, B row-major NxK) -> bf16 MFMA 16x16x32.
// ---------------------------------------------------------------------------

using us8   = __attribute__((ext_vector_type(8))) unsigned short;
using s8v   = __attribute__((ext_vector_type(8))) short;
using f32x4 = __attribute__((ext_vector_type(4))) float;

__device__ __forceinline__ unsigned short f2bf(float f) {
    union { float f; unsigned int u; } c; c.f = f;
    unsigned int r = c.u + 0x7fffu + ((c.u >> 16) & 1u);   // RTN-even
    return (unsigned short)(r >> 16);
}
__device__ __forceinline__ float bf2f(unsigned short u) {
    union { unsigned int u; float f; } c; c.u = ((unsigned int)u) << 16;
    return c.f;
}

// -------------------------- fp32 -> bf16 convert ---------------------------
__global__ void cvt_f32_bf16(const float* __restrict__ in,
                             unsigned short* __restrict__ out, int n) {
    int i = (blockIdx.x * blockDim.x + threadIdx.x) * 8;
    if (i + 8 > n) return;
    float4 a = *(const float4*)(in + i);
    float4 b = *(const float4*)(in + i + 4);
    us8 o;
    o[0] = f2bf(a.x); o[1] = f2bf(a.y); o[2] = f2bf(a.z); o[3] = f2bf(a.w);
    o[4] = f2bf(b.x); o[5] = f2bf(b.y); o[6] = f2bf(b.z); o[7] = f2bf(b.w);
    *(us8*)(out + i) = o;
}

// ----------------------------- bf16 NT GEMM --------------------------------
// C[m,n] = sum_k A[m,k]*Bt[n,k].  128x128 tile, BK=32, 256 threads (4 waves),
// each wave computes 64x64 via 4x4 grid of 16x16x32 MFMAs.
// MODE 0: store bf16, relu on cols < 2048 (q,k).  MODE 1: fp32 + bias.
template <int MODE>
__global__ __launch_bounds__(256)
void gemm_bt(const unsigned short* __restrict__ A,
             const unsigned short* __restrict__ Bt,
             void* __restrict__ C, const float* __restrict__ bias,
             int M, int N, int K) {
    __shared__ unsigned short As[128 * 32];
    __shared__ unsigned short Bs[128 * 32];

    const int tid  = threadIdx.x;
    const int lane = tid & 63;
    const int wv   = tid >> 6;          // 0..3
    const int wr   = wv >> 1, wc = wv & 1;
    const int tM   = blockIdx.x * 128;
    const int tN   = blockIdx.y * 128;

    f32x4 acc[4][4] = {};

    const int srow = tid >> 2;          // 0..63
    const int sseg = (tid & 3) * 8;     // 0,8,16,24
    const unsigned short* Ag = A + (tM + srow) * K + sseg;
    const unsigned short* Bg = Bt + (tN + srow) * K + sseg;
    const int loff = srow * 32 + sseg;

    const int mrow = lane & 15;
    const int kq   = (lane >> 4) * 8;

    for (int k0 = 0; k0 < K; k0 += 32) {
        us8 a0 = *(const us8*)(Ag + k0);
        us8 a1 = *(const us8*)(Ag + 64 * K + k0);
        us8 b0 = *(const us8*)(Bg + k0);
        us8 b1 = *(const us8*)(Bg + 64 * K + k0);
        __syncthreads();
        *(us8*)&As[loff]           = a0;
        *(us8*)&As[loff + 64 * 32] = a1;
        *(us8*)&Bs[loff]           = b0;
        *(us8*)&Bs[loff + 64 * 32] = b1;
        __syncthreads();
        s8v af[4], bf[4];
#pragma unroll
        for (int mi = 0; mi < 4; ++mi)
            af[mi] = *(const s8v*)&As[(wr * 64 + mi * 16 + mrow) * 32 + kq];
#pragma unroll
        for (int ni = 0; ni < 4; ++ni)
            bf[ni] = *(const s8v*)&Bs[(wc * 64 + ni * 16 + mrow) * 32 + kq];
#pragma unroll
        for (int mi = 0; mi < 4; ++mi)
#pragma unroll
            for (int ni = 0; ni < 4; ++ni)
                acc[mi][ni] = __builtin_amdgcn_mfma_f32_16x16x32_bf16(
                    af[mi], bf[ni], acc[mi][ni], 0, 0, 0);
    }

    const int crow0 = (lane >> 4) * 4;
    const int ccol  = lane & 15;
#pragma unroll
    for (int mi = 0; mi < 4; ++mi)
#pragma unroll
        for (int ni = 0; ni < 4; ++ni) {
            int row = tM + wr * 64 + mi * 16 + crow0;
            int col = tN + wc * 64 + ni * 16 + ccol;
#pragma unroll
            for (int r = 0; r < 4; ++r) {
                float v = acc[mi][ni][r];
                if (MODE == 0) {
                    if (col < 2048) v = fmaxf(v, 0.f);
                    ((unsigned short*)C)[(row + r) * N + col] = f2bf(v);
                } else {
                    ((float*)C)[(row + r) * N + col] = v + bias[col];
                }
            }
        }
}

// ------------------- vk = Vpad @ reluK^T  (per b,h; 33x32) -----------------
__global__ __launch_bounds__(256)
void lite_vk(const unsigned short* __restrict__ qkv, float* __restrict__ vkws) {
    const int bh = blockIdx.x;          // 0..127
    const int b = bh >> 5, h = bh & 31;
    __shared__ unsigned short Kt[64 * 32];
    __shared__ unsigned short Vt[64 * 32];
    const int t = threadIdx.x;
    const int e = t & 31, dg = t >> 5;  // dg 0..7
    float acc0 = 0, acc1 = 0, acc2 = 0, acc3 = 0, accK = 0;
    const int lrow = t >> 2, lseg = (t & 3) * 8;
    const int rowbase = b * 4096;
    const int ko = 1024 + h * 32 + lseg;
    const int vo = 2048 + h * 32 + lseg;

    for (int n0 = 0; n0 < 4096; n0 += 64) {
        int g = (rowbase + n0 + lrow) * 3072;
        us8 kv = *(const us8*)(qkv + g + ko);
        us8 vv = *(const us8*)(qkv + g + vo);
        __syncthreads();
        *(us8*)&Kt[lrow * 32 + lseg] = kv;
        *(us8*)&Vt[lrow * 32 + lseg] = vv;
        __syncthreads();
#pragma unroll 8
        for (int nn = 0; nn < 64; ++nn) {
            float kk = fmaxf(bf2f(Kt[nn * 32 + e]), 0.f);  // already relu'd; harmless
            acc0 += bf2f(Vt[nn * 32 + dg])      * kk;
            acc1 += bf2f(Vt[nn * 32 + dg + 8])  * kk;
            acc2 += bf2f(Vt[nn * 32 + dg + 16]) * kk;
            acc3 += bf2f(Vt[nn * 32 + dg + 24]) * kk;
            accK += kk;
        }
    }
    float* vkb = vkws + bh * (33 * 32);
    vkb[(dg)      * 32 + e] = acc0;
    vkb[(dg + 8)  * 32 + e] = acc1;
    vkb[(dg + 16) * 32 + e] = acc2;
    vkb[(dg + 24) * 32 + e] = acc3;
    if (dg == 0) vkb[32 * 32 + e] = accK;
}

// --------------- y = (vk @ reluQ) normalized by pad row --------------------
__global__ __launch_bounds__(256)
void lite_apply(const unsigned short* __restrict__ qkv,
                const float* __restrict__ vkws,
                unsigned short* __restrict__ yb) {
    const int bh = blockIdx.x;          // 128
    const int nb = blockIdx.y;          // 64
    const int b = bh >> 5, h = bh & 31;
    __shared__ float vks[33 * 33];      // +1 pad: kills 32-way bank conflict
    __shared__ unsigned short Qt[64 * 32];
    const int t = threadIdx.x;
    for (int i = t; i < 33 * 32; i += 256)
        vks[(i >> 5) * 33 + (i & 31)] = vkws[bh * (33 * 32) + i];
    const int lrow = t >> 2, lseg = (t & 3) * 8;
    int g = (b * 4096 + nb * 64 + lrow) * 3072 + h * 32 + lseg;
    *(us8*)&Qt[lrow * 32 + lseg] = *(const us8*)(qkv + g);
    __syncthreads();

    const int d = t & 31, ng = t >> 5;
#pragma unroll
    for (int i = 0; i < 8; ++i) {
        int nn = ng * 8 + i;
        float s = 0.f, den = 0.f;
#pragma unroll
        for (int e2 = 0; e2 < 32; ++e2) {
            float qe = fmaxf(bf2f(Qt[nn * 32 + e2]), 0.f);
            s   += vks[d * 33 + e2]  * qe;
            den += vks[32 * 33 + e2] * qe;
        }
        int n = nb * 64 + nn;
        yb[(b * 4096 + n) * 1024 + h * 32 + d] = f2bf(s / (den + 1e-15f));
    }
}

// ---------------------------------------------------------------------------
extern "C" void kernel_launch(void* const* d_in, const int* in_sizes, int n_in,
                              void* d_out, int out_size, void* d_ws, size_t ws_size,
                              hipStream_t stream) {
    const float* x     = (const float*)d_in[0];   // (4,4096,1024)
    const float* Wqkv  = (const float*)d_in[1];   // (3072,1024)
    const float* Wproj = (const float*)d_in[2];   // (1024,1024)
    const float* bproj = (const float*)d_in[3];   // (1024,)
    float* out = (float*)d_out;                   // (4,4096,1024) fp32

    const int M = 16384, Cdim = 1024, O1 = 3072;

    unsigned short* xb     = (unsigned short*)d_ws;
    unsigned short* wqkvb  = xb + (size_t)M * Cdim;
    unsigned short* wprojb = wqkvb + (size_t)O1 * Cdim;
    unsigned short* qkvb   = wprojb + (size_t)Cdim * Cdim;
    unsigned short* ybuf   = qkvb + (size_t)M * O1;
    float* vkws            = (float*)(ybuf + (size_t)M * Cdim);
    // total ws use: ~176.7 MB

    cvt_f32_bf16<<<(M * Cdim / 8 + 255) / 256, 256, 0, stream>>>(x, xb, M * Cdim);
    cvt_f32_bf16<<<(O1 * Cdim / 8 + 255) / 256, 256, 0, stream>>>(Wqkv, wqkvb, O1 * Cdim);
    cvt_f32_bf16<<<(Cdim * Cdim / 8 + 255) / 256, 256, 0, stream>>>(Wproj, wprojb, Cdim * Cdim);

    gemm_bt<0><<<dim3(M / 128, O1 / 128), 256, 0, stream>>>(
        xb, wqkvb, (void*)qkvb, nullptr, M, O1, Cdim);

    lite_vk<<<128, 256, 0, stream>>>(qkvb, vkws);
    lite_apply<<<dim3(128, 64), 256, 0, stream>>>(qkvb, vkws, ybuf);

    gemm_bt<1><<<dim3(M / 128, Cdim / 128), 256, 0, stream>>>(
        ybuf, wprojb, (void*)out, bproj, M, Cdim, Cdim);
}

// Round 2
// 387.295 us; speedup vs baseline: 1.8078x; 1.8078x over previous
//
#include <hip/hip_runtime.h>

// ---------------------------------------------------------------------------
// LiteMLA: B=4, N=4096, C=1024, D=32, h=32 heads.
//   qkv = x @ W_qkv^T            (16384 x 3072, K=1024)   [relu on q,k cols]
//   per (b,h): vk[d,e] = sum_n Vpad[d,n]*reluK[e,n]   (33x32, reduce N=4096)
//              y[d,n]  = (sum_e vk[d,e]*reluQ[e,n]) / (sum_e vk[32,e]*reluQ[e,n] + eps)
//   out = y @ W_proj^T + b_proj  (16384 x 1024, K=1024)
// GEMMs: NT bf16 MFMA 16x16x32 with global_load_lds width-16 staging (m97).
// Attention apply: K=32 single-step MFMA per (b,h), vk in bf16 hi+lo split.
// ---------------------------------------------------------------------------

using us8   = __attribute__((ext_vector_type(8))) unsigned short;
using us4   = __attribute__((ext_vector_type(4))) unsigned short;
using s8v   = __attribute__((ext_vector_type(8))) short;
using f32x4 = __attribute__((ext_vector_type(4))) float;

__device__ __forceinline__ unsigned short f2bf(float f) {
    union { float f; unsigned int u; } c; c.f = f;
    unsigned int r = c.u + 0x7fffu + ((c.u >> 16) & 1u);   // RTN-even
    return (unsigned short)(r >> 16);
}
__device__ __forceinline__ float bf2f(unsigned short u) {
    union { unsigned int u; float f; } c; c.u = ((unsigned int)u) << 16;
    return c.f;
}

// async global->LDS, 16B per lane; LDS dest = wave-uniform base + lane*16
__device__ __forceinline__ void async16(const unsigned short* g, unsigned short* l) {
    __builtin_amdgcn_global_load_lds(
        (const __attribute__((address_space(1))) unsigned int*)g,
        (__attribute__((address_space(3))) unsigned int*)l, 16, 0, 0);
}

// -------------------------- fp32 -> bf16 convert ---------------------------
__global__ void cvt_f32_bf16(const float* __restrict__ in,
                             unsigned short* __restrict__ out, int n) {
    int i = (blockIdx.x * blockDim.x + threadIdx.x) * 8;
    if (i + 8 > n) return;
    float4 a = *(const float4*)(in + i);
    float4 b = *(const float4*)(in + i + 4);
    us8 o;
    o[0] = f2bf(a.x); o[1] = f2bf(a.y); o[2] = f2bf(a.z); o[3] = f2bf(a.w);
    o[4] = f2bf(b.x); o[5] = f2bf(b.y); o[6] = f2bf(b.z); o[7] = f2bf(b.w);
    *(us8*)(out + i) = o;
}

__global__ void zero_f32(float* __restrict__ p, int n) {
    int i = blockIdx.x * blockDim.x + threadIdx.x;
    if (i < n) p[i] = 0.f;
}

// ----------------------------- bf16 NT GEMM --------------------------------
// C[m,n] = sum_k A[m,k]*Bt[n,k].  128x128 tile, BK=32, 256 threads (4 waves),
// each wave computes 64x64 via 4x4 grid of 16x16x32 MFMAs.
// Staging via global_load_lds width=16: wave wv stages 32 rows of A and B
// (2 calls x 16 rows each; lane l -> row l>>2, seg (l&3)*8).
// MODE 0: store bf16, relu on cols < 2048 (q,k).  MODE 1: fp32 + bias.
template <int MODE>
__global__ __launch_bounds__(256)
void gemm_bt(const unsigned short* __restrict__ A,
             const unsigned short* __restrict__ Bt,
             void* __restrict__ C, const float* __restrict__ bias,
             int M, int N, int K) {
    __shared__ unsigned short As[128 * 32];
    __shared__ unsigned short Bs[128 * 32];

    const int tid  = threadIdx.x;
    const int lane = tid & 63;
    const int wv   = tid >> 6;          // 0..3
    const int wr   = wv >> 1, wc = wv & 1;
    const int tM   = blockIdx.x * 128;
    const int tN   = blockIdx.y * 128;

    f32x4 acc[4][4] = {};

    const unsigned short* Ag = A + (size_t)(tM + wv * 32 + (lane >> 2)) * K + (lane & 3) * 8;
    const unsigned short* Bg = Bt + (size_t)(tN + wv * 32 + (lane >> 2)) * K + (lane & 3) * 8;
    unsigned short* AsW = &As[(wv * 32) * 32];
    unsigned short* BsW = &Bs[(wv * 32) * 32];

    const int mrow = lane & 15;
    const int kq   = (lane >> 4) * 8;

    for (int k0 = 0; k0 < K; k0 += 32) {
        __syncthreads();                       // previous iter's reads done
        async16(Ag + k0,          AsW);
        async16(Ag + 16 * K + k0, AsW + 16 * 32);
        async16(Bg + k0,          BsW);
        async16(Bg + 16 * K + k0, BsW + 16 * 32);
        asm volatile("s_waitcnt vmcnt(0)" ::: "memory");
        __syncthreads();                       // all waves' data in LDS
        s8v af[4], bf[4];
#pragma unroll
        for (int mi = 0; mi < 4; ++mi)
            af[mi] = *(const s8v*)&As[(wr * 64 + mi * 16 + mrow) * 32 + kq];
#pragma unroll
        for (int ni = 0; ni < 4; ++ni)
            bf[ni] = *(const s8v*)&Bs[(wc * 64 + ni * 16 + mrow) * 32 + kq];
#pragma unroll
        for (int mi = 0; mi < 4; ++mi)
#pragma unroll
            for (int ni = 0; ni < 4; ++ni)
                acc[mi][ni] = __builtin_amdgcn_mfma_f32_16x16x32_bf16(
                    af[mi], bf[ni], acc[mi][ni], 0, 0, 0);
    }

    const int crow0 = (lane >> 4) * 4;
    const int ccol  = lane & 15;
#pragma unroll
    for (int mi = 0; mi < 4; ++mi)
#pragma unroll
        for (int ni = 0; ni < 4; ++ni) {
            int row = tM + wr * 64 + mi * 16 + crow0;
            int col = tN + wc * 64 + ni * 16 + ccol;
#pragma unroll
            for (int r = 0; r < 4; ++r) {
                float v = acc[mi][ni][r];
                if (MODE == 0) {
                    if (col < 2048) v = fmaxf(v, 0.f);
                    ((unsigned short*)C)[(size_t)(row + r) * N + col] = f2bf(v);
                } else {
                    ((float*)C)[(size_t)(row + r) * N + col] = v + bias[col];
                }
            }
        }
}

// ------------- vk partial: 1024 blocks, atomicAdd into vkws ----------------
// grid (128 bh, 8 chunks of 512 tokens). Thread t: e = t&31, d = (t>>5)*4..+3.
__global__ __launch_bounds__(256)
void lite_vk(const unsigned short* __restrict__ qkv, float* __restrict__ vkws) {
    const int bh = blockIdx.x, ch = blockIdx.y;
    const int b = bh >> 5, h = bh & 31;
    __shared__ unsigned short Kt[64 * 32];
    __shared__ unsigned short Vt[64 * 32];
    const int t = threadIdx.x;
    const int e = t & 31, dg = (t >> 5) * 4;
    float acc0 = 0, acc1 = 0, acc2 = 0, acc3 = 0, accK = 0;
    const int lrow = t >> 2, lseg = (t & 3) * 8;
    const int ko = 1024 + h * 32 + lseg;
    const int vo = 2048 + h * 32 + lseg;
    const int rowbase = b * 4096 + ch * 512;

    for (int n0 = 0; n0 < 512; n0 += 64) {
        int g = (rowbase + n0 + lrow) * 3072;
        us8 kv = *(const us8*)(qkv + g + ko);
        us8 vv = *(const us8*)(qkv + g + vo);
        __syncthreads();
        *(us8*)&Kt[lrow * 32 + lseg] = kv;
        *(us8*)&Vt[lrow * 32 + lseg] = vv;
        __syncthreads();
#pragma unroll 8
        for (int nn = 0; nn < 64; ++nn) {
            float kk = bf2f(Kt[nn * 32 + e]);       // K already relu'd in GEMM1
            us4 v4 = *(const us4*)&Vt[nn * 32 + dg];
            acc0 += bf2f(v4[0]) * kk;
            acc1 += bf2f(v4[1]) * kk;
            acc2 += bf2f(v4[2]) * kk;
            acc3 += bf2f(v4[3]) * kk;
            accK += kk;
        }
    }
    float* vkb = vkws + bh * (33 * 32);
    atomicAdd(&vkb[(dg + 0) * 32 + e], acc0);
    atomicAdd(&vkb[(dg + 1) * 32 + e], acc1);
    atomicAdd(&vkb[(dg + 2) * 32 + e], acc2);
    atomicAdd(&vkb[(dg + 3) * 32 + e], acc3);
    if (dg == 0) atomicAdd(&vkb[32 * 32 + e], accK);
}

// --------------- y = (vk @ reluQ) / pad-row, MFMA K=32 ---------------------
// grid (128 bh, 16 chunks of 256 tokens), 256 threads (4 waves x 64 tokens).
// B-frags: vk rows d (hi+lo bf16); frag2 row 32 = pad row, rows 33..47 zero.
__global__ __launch_bounds__(256)
void lite_apply(const unsigned short* __restrict__ qkv,
                const float* __restrict__ vkws,
                unsigned short* __restrict__ yb) {
    const int bh = blockIdx.x, nb = blockIdx.y;
    const int b = bh >> 5, h = bh & 31;
    __shared__ unsigned short vkh[48 * 32];
    __shared__ unsigned short vkl[48 * 32];
    const int t = threadIdx.x;
    for (int i = t; i < 48 * 32; i += 256) {
        float v = (i < 33 * 32) ? vkws[bh * (33 * 32) + i] : 0.f;
        unsigned short hi = f2bf(v);
        vkh[i] = hi;
        vkl[i] = f2bf(v - bf2f(hi));
    }
    __syncthreads();

    const int lane = t & 63, wv = t >> 6;
    const int col = lane & 15, quad = lane >> 4;
    s8v b0h = *(const s8v*)&vkh[(col)      * 32 + quad * 8];
    s8v b0l = *(const s8v*)&vkl[(col)      * 32 + quad * 8];
    s8v b1h = *(const s8v*)&vkh[(16 + col) * 32 + quad * 8];
    s8v b1l = *(const s8v*)&vkl[(16 + col) * 32 + quad * 8];
    s8v b2h = *(const s8v*)&vkh[(32 + col) * 32 + quad * 8];
    s8v b2l = *(const s8v*)&vkl[(32 + col) * 32 + quad * 8];

    const int ntile = nb * 256 + wv * 64;
#pragma unroll
    for (int mi = 0; mi < 4; ++mi) {
        int tokA = ntile + mi * 16 + col;      // A row: m = lane&15
        const unsigned short* qp =
            qkv + (size_t)(b * 4096 + tokA) * 3072 + h * 32 + quad * 8;
        s8v a = *(const s8v*)qp;
        f32x4 n0 = {}, n1 = {}, dd = {};
        n0 = __builtin_amdgcn_mfma_f32_16x16x32_bf16(a, b0h, n0, 0, 0, 0);
        n0 = __builtin_amdgcn_mfma_f32_16x16x32_bf16(a, b0l, n0, 0, 0, 0);
        n1 = __builtin_amdgcn_mfma_f32_16x16x32_bf16(a, b1h, n1, 0, 0, 0);
        n1 = __builtin_amdgcn_mfma_f32_16x16x32_bf16(a, b1l, n1, 0, 0, 0);
        dd = __builtin_amdgcn_mfma_f32_16x16x32_bf16(a, b2h, dd, 0, 0, 0);
        dd = __builtin_amdgcn_mfma_f32_16x16x32_bf16(a, b2l, dd, 0, 0, 0);
#pragma unroll
        for (int r = 0; r < 4; ++r) {
            float den = __shfl(dd[r], lane & 48, 64) + 1e-15f;  // col 0 of quad
            int tok = ntile + mi * 16 + quad * 4 + r;           // C row
            size_t o = (size_t)(b * 4096 + tok) * 1024 + h * 32;
            yb[o + col]      = f2bf(n0[r] / den);
            yb[o + 16 + col] = f2bf(n1[r] / den);
        }
    }
}

// ---------------------------------------------------------------------------
extern "C" void kernel_launch(void* const* d_in, const int* in_sizes, int n_in,
                              void* d_out, int out_size, void* d_ws, size_t ws_size,
                              hipStream_t stream) {
    const float* x     = (const float*)d_in[0];   // (4,4096,1024)
    const float* Wqkv  = (const float*)d_in[1];   // (3072,1024)
    const float* Wproj = (const float*)d_in[2];   // (1024,1024)
    const float* bproj = (const float*)d_in[3];   // (1024,)
    float* out = (float*)d_out;                   // (4,4096,1024) fp32

    const int M = 16384, Cdim = 1024, O1 = 3072;

    unsigned short* xb     = (unsigned short*)d_ws;
    unsigned short* wqkvb  = xb + (size_t)M * Cdim;
    unsigned short* wprojb = wqkvb + (size_t)O1 * Cdim;
    unsigned short* qkvb   = wprojb + (size_t)Cdim * Cdim;
    unsigned short* ybuf   = qkvb + (size_t)M * O1;
    float* vkws            = (float*)(ybuf + (size_t)M * Cdim);
    // ws use: ~177 MB

    cvt_f32_bf16<<<(M * Cdim / 8 + 255) / 256, 256, 0, stream>>>(x, xb, M * Cdim);
    cvt_f32_bf16<<<(O1 * Cdim / 8 + 255) / 256, 256, 0, stream>>>(Wqkv, wqkvb, O1 * Cdim);
    cvt_f32_bf16<<<(Cdim * Cdim / 8 + 255) / 256, 256, 0, stream>>>(Wproj, wprojb, Cdim * Cdim);
    zero_f32<<<(128 * 33 * 32 + 255) / 256, 256, 0, stream>>>(vkws, 128 * 33 * 32);

    gemm_bt<0><<<dim3(M / 128, O1 / 128), 256, 0, stream>>>(
        xb, wqkvb, (void*)qkvb, nullptr, M, O1, Cdim);

    lite_vk<<<dim3(128, 8), 256, 0, stream>>>(qkvb, vkws);
    lite_apply<<<dim3(128, 16), 256, 0, stream>>>(qkvb, vkws, ybuf);

    gemm_bt<1><<<dim3(M / 128, Cdim / 128), 256, 0, stream>>>(
        ybuf, wprojb, (void*)out, bproj, M, Cdim, Cdim);
}